// Round 7
// baseline (973.662 us; speedup 1.0000x reference)
//
#include <hip/hip_runtime.h>

// Deformable KPN, bf16 MFMA implicit-GEMM pipeline, round 7.
// vs round 6:
//  - conv_mfma/conv7_combine: triple-buffered staging, raw s_barrier +
//    counted s_waitcnt vmcnt(7) (no full drain in main loop)
//  - A-fragments prefetched per 3-tap row, double-buffered in registers
//  - __launch_bounds__(256,2); vectorized convert_data stores

typedef __attribute__((ext_vector_type(8))) short short8;
typedef __attribute__((ext_vector_type(4))) float f32x4;

__device__ __forceinline__ unsigned short f2bf(float f) {
    unsigned int b = __float_as_uint(f);
    b = (b + 0x7fffu + ((b >> 16) & 1u)) >> 16;
    return (unsigned short)b;
}
__device__ __forceinline__ float bf2f(unsigned int u) {
    return __uint_as_float(u << 16);
}
__device__ __forceinline__ unsigned int pack2(float a, float b) {
    return (unsigned int)f2bf(a) | ((unsigned int)f2bf(b) << 16);
}

// ---------------- fused weight packing + zero-page ----------------
__global__ __launch_bounds__(256) void prep_kern(
    const float* __restrict__ w1, const float* __restrict__ w2,
    const float* __restrict__ w3, const float* __restrict__ w5,
    const float* __restrict__ w6, const float* __restrict__ w7,
    unsigned short* __restrict__ wpk)
{
    int idx = blockIdx.x * 256 + threadIdx.x;
    if (idx < 460800) {
        const float* w; int off, CinR, CoutR, CoutP, nch, remap;
        if (idx < 18432)       { w = w1; off = 0;      CinR = 15;  CoutR = 64;  CoutP = 64;  nch = 1; remap = 0; }
        else if (idx < 92160)  { w = w2; off = 18432;  CinR = 64;  CoutR = 128; CoutP = 128; nch = 2; remap = 0; }
        else if (idx < 239616) { w = w3; off = 92160;  CinR = 128; CoutR = 81;  CoutP = 128; nch = 4; remap = 0; }
        else if (idx < 387072) { w = w5; off = 239616; CinR = 224; CoutR = 64;  CoutP = 64;  nch = 8; remap = 1; }
        else if (idx < 423936) { w = w6; off = 387072; CinR = 64;  CoutR = 64;  CoutP = 64;  nch = 2; remap = 0; }
        else                   { w = w7; off = 423936; CinR = 64;  CoutR = 27;  CoutP = 64;  nch = 2; remap = 0; }
        int li = idx - off;
        int kin = li & 31;
        int t = li >> 5;
        int co = t % CoutP; t /= CoutP;
        int chunk = t % nch;
        int tap = t / nch;
        int ci = chunk * 32 + kin;
        int cs = -1;
        if (remap) {
            if (ci < 15) cs = ci;
            else if (ci >= 16 && ci <= 224) cs = ci - 1;
        } else {
            if (ci < CinR) cs = ci;
        }
        float val = 0.f;
        if (co < CoutR && cs >= 0)
            val = w[(co * CinR + cs) * 9 + tap];
        wpk[idx] = f2bf(val);
    } else if (idx < 460800 + 8192) {
        wpk[idx] = 0;
    }
}

// ---------------- data -> concat NHWC bf16 ----------------
__global__ __launch_bounds__(256) void convert_data(
    const float* __restrict__ data, unsigned short* __restrict__ concat)
{
    int i = blockIdx.x * 256 + threadIdx.x;   // B*H*W
    int b = i >> 16, p = i & 65535;
    unsigned int w[8];
#pragma unroll
    for (int k = 0; k < 7; ++k)
        w[k] = pack2(data[(b * 15 + 2 * k) * 65536 + p],
                     data[(b * 15 + 2 * k + 1) * 65536 + p]);
    w[7] = (unsigned int)f2bf(data[(b * 15 + 14) * 65536 + p]);
    uint4* d = (uint4*)(concat + i * 232);
    d[0] = make_uint4(w[0], w[1], w[2], w[3]);
    d[1] = make_uint4(w[4], w[5], w[6], w[7]);
}

// ---------------- data -> packed sampling texture [B][D][HW][4] bf16 ----------------
__global__ __launch_bounds__(256) void pack_dpk(
    const float* __restrict__ data, unsigned short* __restrict__ dpk)
{
    int i = blockIdx.x * 256 + threadIdx.x;   // B*D*H*W
    int bd = i >> 16, p = i & 65535;
    unsigned int w0 = pack2(data[(bd * 3 + 0) * 65536 + p],
                            data[(bd * 3 + 1) * 65536 + p]);
    unsigned int w1 = (unsigned int)f2bf(data[(bd * 3 + 2) * 65536 + p]);
    *(uint2*)(dpk + i * 4) = make_uint2(w0, w1);
}

// ---------------- MFMA conv (counted-vmcnt pipeline) ----------------
__global__ __launch_bounds__(256, 2) void conv_mfma(
    const unsigned short* __restrict__ src, int srcCs, int srcOff,
    const unsigned short* __restrict__ wp, const float* __restrict__ bias,
    int nch, int Cout, int Cout_pad,
    void* __restrict__ dst, int dstCs, int dstOff, int mode, int relu,
    const uint4* __restrict__ zp)
{
    __shared__ uint4 ldsb[3 * 1584];         // 3 bufs x 4kb x 396(=66x6) x 16B
    const int tid = threadIdx.x;
    const int lane = tid & 63;
    const int wv = tid >> 6;
    const int bx = blockIdx.x, b = blockIdx.y, bz = blockIdx.z;
    const int x0 = (bx & 3) * 64, y0 = (bx >> 2) * 4;
    const int l15 = lane & 15, l4 = lane >> 4;
    const int mtc = min(4, (Cout - bz * 64 + 15) >> 4);

    f32x4 acc[4][4];
#pragma unroll
    for (int m = 0; m < 4; ++m)
#pragma unroll
        for (int nt = 0; nt < 4; ++nt) acc[m][nt] = (f32x4)0.f;

    auto stage = [&](int bufi, int chunk) {   // 7 global_load_lds per wave
        uint4* d0 = ldsb + bufi * 1584 + wv * 396;
        int ch = srcOff + chunk * 32 + wv * 8;
        bool chok = (ch + 8 <= srcCs);
        const unsigned short* sbase = src + ch;
#pragma unroll
        for (int it = 0; it < 7; ++it) {
            int r = it * 64 + lane;
            if (r < 396) {
                int hy = r / 66, hx = r - hy * 66;
                int y = y0 - 1 + hy, x = x0 - 1 + hx;
                const uint4* g;
                if (chok && (unsigned)y < 256u && (unsigned)x < 256u)
                    g = (const uint4*)(sbase + (b * 65536 + y * 256 + x) * srcCs);
                else
                    g = zp + lane;
                __builtin_amdgcn_global_load_lds(
                    (const __attribute__((address_space(1))) void*)g,
                    (__attribute__((address_space(3))) void*)(d0 + it * 64),
                    16, 0, 0);
            }
        }
    };

    stage(0, 0);
    if (nch > 1) stage(1, 1);
    for (int c = 0; c < nch; ++c) {
        __builtin_amdgcn_s_barrier();         // all waves done with buf[(c+2)%3]
        if (c + 2 < nch) stage((c + 2) % 3, c + 2);
        if (c + 1 < nch) asm volatile("s_waitcnt vmcnt(7)" ::: "memory");
        else             asm volatile("s_waitcnt vmcnt(0)" ::: "memory");
        __builtin_amdgcn_s_barrier();         // all waves' stage(c) landed

        const uint4* lb = ldsb + (c % 3) * 1584;
        short8 A0[3][4], A1[3][4], A2[3][4];
        auto loadrow = [&](short8 (&A)[3][4], int row) {
#pragma unroll
            for (int t = 0; t < 3; ++t)
#pragma unroll
                for (int m = 0; m < 4; ++m)
                    if (m < mtc)
                        A[t][m] = *(const short8*)(wp +
                            (((row * 3 + t) * nch + c) * Cout_pad +
                             bz * 64 + m * 16 + l15) * 32 + l4 * 8);
        };
        auto mfmarow = [&](short8 (&A)[3][4], int row) {
#pragma unroll
            for (int t = 0; t < 3; ++t) {
#pragma unroll
                for (int nt = 0; nt < 4; ++nt) {
                    int hx = nt * 16 + l15 + t;
                    int hy = wv + row;
                    short8 bf = __builtin_bit_cast(short8,
                        lb[l4 * 396 + hy * 66 + hx]);
#pragma unroll
                    for (int m = 0; m < 4; ++m)
                        if (m < mtc)
                            acc[m][nt] = __builtin_amdgcn_mfma_f32_16x16x32_bf16(
                                A[t][m], bf, acc[m][nt], 0, 0, 0);
                }
            }
        };
        loadrow(A0, 0);
        loadrow(A1, 1);
        mfmarow(A0, 0);
        loadrow(A2, 2);
        mfmarow(A1, 1);
        mfmarow(A2, 2);
    }

    const int y = y0 + wv;
#pragma unroll
    for (int m = 0; m < 4; ++m) {
        if (m >= mtc) continue;
        int co0 = bz * 64 + m * 16 + l4 * 4;
#pragma unroll
        for (int nt = 0; nt < 4; ++nt) {
            int x = x0 + nt * 16 + l15;
            float v[4];
#pragma unroll
            for (int e = 0; e < 4; ++e) {
                int co = co0 + e;
                float f = acc[m][nt][e] + ((co < Cout) ? bias[co] : 0.f);
                if (relu) f = fmaxf(f, 0.f);
                v[e] = f;
            }
            if (mode == 0) {
                unsigned short* d = (unsigned short*)dst +
                    ((b * 65536 + y * 256 + x) * dstCs + dstOff + co0);
                if (co0 + 3 < Cout) {
                    uint2 pk = make_uint2(pack2(v[0], v[1]), pack2(v[2], v[3]));
                    *(uint2*)d = pk;
                } else {
#pragma unroll
                    for (int e = 0; e < 4; ++e)
                        if (co0 + e < Cout) d[e] = f2bf(v[e]);
                }
            } else {
                float* d = (float*)dst + (b * dstCs + co0) * 65536 + y * 256 + x;
#pragma unroll
                for (int e = 0; e < 4; ++e)
                    if (co0 + e < Cout) d[e * 65536] = v[e];
            }
        }
    }
}

// ---------------- conv7 (64->27) + combine, fused ----------------
__global__ __launch_bounds__(256, 2) void conv7_combine(
    const unsigned short* __restrict__ src,     // h2, NHWC 64
    const unsigned short* __restrict__ wp,      // wp7
    const float* __restrict__ bias,             // wc_b3 (27)
    const unsigned short* __restrict__ concat,  // samples at ch144..224
    float* __restrict__ res_i, float* __restrict__ outp,
    const uint4* __restrict__ zp)
{
    __shared__ uint4 ldsb[3 * 1584];
    float* wlds = (float*)ldsb;                 // [wv][px(64)][co stride 33] 33792B
    const int tid = threadIdx.x;
    const int lane = tid & 63;
    const int wv = tid >> 6;
    const int bx = blockIdx.x, b = blockIdx.y;
    const int x0 = (bx & 3) * 64, y0 = (bx >> 2) * 4;
    const int l15 = lane & 15, l4 = lane >> 4;

    f32x4 acc[2][4];
#pragma unroll
    for (int m = 0; m < 2; ++m)
#pragma unroll
        for (int nt = 0; nt < 4; ++nt) acc[m][nt] = (f32x4)0.f;

    auto stage = [&](int bufi, int chunk) {
        uint4* d0 = ldsb + bufi * 1584 + wv * 396;
        int ch = chunk * 32 + wv * 8;
        const unsigned short* sbase = src + ch;
#pragma unroll
        for (int it = 0; it < 7; ++it) {
            int r = it * 64 + lane;
            if (r < 396) {
                int hy = r / 66, hx = r - hy * 66;
                int y = y0 - 1 + hy, x = x0 - 1 + hx;
                const uint4* g;
                if ((unsigned)y < 256u && (unsigned)x < 256u)
                    g = (const uint4*)(sbase + (b * 65536 + y * 256 + x) * 64);
                else
                    g = zp + lane;
                __builtin_amdgcn_global_load_lds(
                    (const __attribute__((address_space(1))) void*)g,
                    (__attribute__((address_space(3))) void*)(d0 + it * 64),
                    16, 0, 0);
            }
        }
    };

    stage(0, 0);
    stage(1, 1);
    for (int c = 0; c < 2; ++c) {
        __builtin_amdgcn_s_barrier();
        if (c + 1 < 2) asm volatile("s_waitcnt vmcnt(7)" ::: "memory");
        else           asm volatile("s_waitcnt vmcnt(0)" ::: "memory");
        __builtin_amdgcn_s_barrier();

        const uint4* lb = ldsb + c * 1584;
        short8 A0[3][2], A1[3][2], A2[3][2];
        auto loadrow = [&](short8 (&A)[3][2], int row) {
#pragma unroll
            for (int t = 0; t < 3; ++t)
#pragma unroll
                for (int m = 0; m < 2; ++m)
                    A[t][m] = *(const short8*)(wp +
                        (((row * 3 + t) * 2 + c) * 64 + m * 16 + l15) * 32 + l4 * 8);
        };
        auto mfmarow = [&](short8 (&A)[3][2], int row) {
#pragma unroll
            for (int t = 0; t < 3; ++t) {
#pragma unroll
                for (int nt = 0; nt < 4; ++nt) {
                    int hx = nt * 16 + l15 + t;
                    int hy = wv + row;
                    short8 bf = __builtin_bit_cast(short8,
                        lb[l4 * 396 + hy * 66 + hx]);
#pragma unroll
                    for (int m = 0; m < 2; ++m)
                        acc[m][nt] = __builtin_amdgcn_mfma_f32_16x16x32_bf16(
                            A[t][m], bf, acc[m][nt], 0, 0, 0);
                }
            }
        };
        loadrow(A0, 0);
        loadrow(A1, 1);
        mfmarow(A0, 0);
        loadrow(A2, 2);
        mfmarow(A1, 1);
        mfmarow(A2, 2);
    }

    // ---- weights -> LDS (px-major, padded stride 33) ----
    __syncthreads();
#pragma unroll
    for (int m = 0; m < 2; ++m) {
        int co0 = m * 16 + l4 * 4;
#pragma unroll
        for (int nt = 0; nt < 4; ++nt) {
            int px = nt * 16 + l15;
#pragma unroll
            for (int e = 0; e < 4; ++e) {
                int co = co0 + e;
                wlds[wv * 2112 + px * 33 + co] =
                    acc[m][nt][e] + ((co < 27) ? bias[co] : 0.f);
            }
        }
    }
    __syncthreads();

    // ---- per-pixel combine ----
    const int r = tid >> 6, px = tid & 63;
    const float* wl = wlds + r * 2112 + px * 33;
    const int y = y0 + r, x = x0 + px;
    const int p = y * 256 + x;
    const unsigned short* cp = concat + (b * 65536 + p) * 232 + 144;
    unsigned int sw[41];
    {
        const uint4* gp = (const uint4*)cp;
#pragma unroll
        for (int k = 0; k < 10; ++k) {
            uint4 t = gp[k];
            sw[4 * k] = t.x; sw[4 * k + 1] = t.y;
            sw[4 * k + 2] = t.z; sw[4 * k + 3] = t.w;
        }
        sw[40] = (unsigned int)cp[80];
    }
    float ov[3] = {0.f, 0.f, 0.f};
#pragma unroll
    for (int g = 0; g < 3; ++g) {
        float rr[3] = {0.f, 0.f, 0.f};
#pragma unroll
        for (int k = 0; k < 9; ++k) {
            int s = g * 9 + k;
            float w = wl[s];
            int L0 = 3 * s;
            float s0 = bf2f((sw[L0 >> 1] >> ((L0 & 1) * 16)) & 0xffffu);
            float s1 = bf2f((sw[(L0 + 1) >> 1] >> (((L0 + 1) & 1) * 16)) & 0xffffu);
            float s2 = bf2f((sw[(L0 + 2) >> 1] >> (((L0 + 2) & 1) * 16)) & 0xffffu);
            rr[0] = fmaf(s0, w, rr[0]);
            rr[1] = fmaf(s1, w, rr[1]);
            rr[2] = fmaf(s2, w, rr[2]);
        }
#pragma unroll
        for (int c = 0; c < 3; ++c) {
            res_i[(b * 9 + g * 3 + c) * 65536 + p] = 3.f * rr[c];
            ov[c] += rr[c];
        }
    }
#pragma unroll
    for (int c = 0; c < 3; ++c)
        outp[(b * 3 + c) * 65536 + p] = ov[c];
}

// ---------------- trilinear: offsets -> samples, packed-texture gathers ----------------
__global__ __launch_bounds__(256) void trilin_kern(
    const unsigned short* __restrict__ dpk, unsigned short* __restrict__ concat,
    float* __restrict__ smp)
{
    int i = blockIdx.x * 256 + threadIdx.x;   // b*65536 + p
    int b = i >> 16, p = i & 65535;
    int y = p >> 8, x = p & 255;
    unsigned short* cptr = concat + i * 232 + 144;

    unsigned int wbuf[41];
    {
        const uint4* gp = (const uint4*)cptr;
#pragma unroll
        for (int k = 0; k < 10; ++k) {
            uint4 t = gp[k];
            wbuf[4 * k] = t.x; wbuf[4 * k + 1] = t.y;
            wbuf[4 * k + 2] = t.z; wbuf[4 * k + 3] = t.w;
        }
        wbuf[40] = (unsigned int)cptr[80];
    }

#pragma unroll
    for (int s = 0; s < 27; ++s) {
        int L0 = 3 * s;
        float o0 = bf2f((wbuf[L0 >> 1] >> ((L0 & 1) * 16)) & 0xffffu);
        float o1 = bf2f((wbuf[(L0 + 1) >> 1] >> (((L0 + 1) & 1) * 16)) & 0xffffu);
        float o2 = bf2f((wbuf[(L0 + 2) >> 1] >> (((L0 + 2) & 1) * 16)) & 0xffffu);

        float kd = (float)(s / 9 - 1);
        float kh = (float)((s / 3) % 3 - 1);
        float kw = (float)(s % 3 - 1);
        float pd = 2.0f + kd + o0;
        float ph = (float)y + kh + o1;
        float pw = (float)x + kw + o2;
        pd = fminf(fmaxf(pd, 0.f), 4.f);
        ph = fminf(fmaxf(ph, 0.f), 255.f);
        pw = fminf(fmaxf(pw, 0.f), 255.f);
        float d0 = floorf(pd), h0 = floorf(ph), w0 = floorf(pw);
        float fd = pd - d0, fh = ph - h0, fw = pw - w0;
        int d0i = (int)d0, h0i = (int)h0, w0i = (int)w0;
        int d1i = min(d0i + 1, 4), h1i = min(h0i + 1, 255), w1i = min(w0i + 1, 255);

        const unsigned short* p0 = dpk + (b * 5 + d0i) * 262144;
        const unsigned short* p1 = dpk + (b * 5 + d1i) * 262144;
        int a00 = ((h0i << 8) + w0i) << 2, a01 = ((h0i << 8) + w1i) << 2;
        int a10 = ((h1i << 8) + w0i) << 2, a11 = ((h1i << 8) + w1i) << 2;
        uint2 q000 = *(const uint2*)(p0 + a00), q001 = *(const uint2*)(p0 + a01);
        uint2 q010 = *(const uint2*)(p0 + a10), q011 = *(const uint2*)(p0 + a11);
        uint2 q100 = *(const uint2*)(p1 + a00), q101 = *(const uint2*)(p1 + a01);
        uint2 q110 = *(const uint2*)(p1 + a10), q111 = *(const uint2*)(p1 + a11);

        float res[3];
#pragma unroll
        for (int c = 0; c < 3; ++c) {
            auto ex = [&](uint2 q) {
                unsigned int u = (c == 0) ? (q.x & 0xffffu)
                              : (c == 1) ? (q.x >> 16) : (q.y & 0xffffu);
                return bf2f(u);
            };
            float r0 = (ex(q000) * (1.f - fw) + ex(q001) * fw) * (1.f - fh)
                     + (ex(q010) * (1.f - fw) + ex(q011) * fw) * fh;
            float r1 = (ex(q100) * (1.f - fw) + ex(q101) * fw) * (1.f - fh)
                     + (ex(q110) * (1.f - fw) + ex(q111) * fw) * fh;
            float r = r0 * (1.f - fd) + r1 * fd;
            res[c] = r;
            smp[((b * 27 + s) * 3 + c) * 65536 + p] = r;
        }
#pragma unroll
        for (int c = 0; c < 3; ++c) {
            int L = L0 + c;
            unsigned int u = (unsigned int)f2bf(res[c]);
            if (L & 1) wbuf[L >> 1] = (wbuf[L >> 1] & 0xffffu) | (u << 16);
            else       wbuf[L >> 1] = (wbuf[L >> 1] & 0xffff0000u) | u;
        }
    }

    wbuf[40] &= 0xffffu;
    uint4* gp = (uint4*)cptr;
#pragma unroll
    for (int k = 0; k < 10; ++k)
        gp[k] = make_uint4(wbuf[4 * k], wbuf[4 * k + 1], wbuf[4 * k + 2], wbuf[4 * k + 3]);
    *(unsigned int*)(cptr + 80) = wbuf[40];
}

extern "C" void kernel_launch(void* const* d_in, const int* in_sizes, int n_in,
                              void* d_out, int out_size, void* d_ws, size_t ws_size,
                              hipStream_t stream)
{
    const float* data   = (const float*)d_in[0];
    const float* enc_w1 = (const float*)d_in[1];
    const float* enc_b1 = (const float*)d_in[2];
    const float* enc_w2 = (const float*)d_in[3];
    const float* enc_b2 = (const float*)d_in[4];
    const float* off_w  = (const float*)d_in[5];
    const float* off_b  = (const float*)d_in[6];
    const float* wc_w1  = (const float*)d_in[7];
    const float* wc_b1  = (const float*)d_in[8];
    const float* wc_w2  = (const float*)d_in[9];
    const float* wc_b2  = (const float*)d_in[10];
    const float* wc_w3  = (const float*)d_in[11];
    const float* wc_b3  = (const float*)d_in[12];

    float* dout  = (float*)d_out;
    float* res_i = dout;                  // [4,3,3,256,256]
    float* outp  = dout + 2359296;        // [4,3,256,256]
    float* smp   = dout + 3145728;        // [4,27,3,256,256] fp32 NCHW

    char* ws = (char*)d_ws;
    unsigned short* concat = (unsigned short*)ws;                      // 121,634,816 B
    unsigned short* buf_a  = (unsigned short*)(ws + 121634816);        // 33,554,432 B
    unsigned short* buf_b  = (unsigned short*)(ws + 155189248);        // 33,554,432 B
    unsigned short* wpk    = (unsigned short*)(ws + 188743680);        // 921,600 B + 16 KB zp
    unsigned short* wp1 = wpk;            // 9*1*64*32  = 18432
    unsigned short* wp2 = wpk + 18432;    // 9*2*128*32 = 73728
    unsigned short* wp3 = wpk + 92160;    // 9*4*128*32 = 147456
    unsigned short* wp5 = wpk + 239616;   // 9*8*64*32  = 147456
    unsigned short* wp6 = wpk + 387072;   // 9*2*64*32  = 36864
    unsigned short* wp7 = wpk + 423936;   // 9*2*64*32  = 36864
    const uint4* zp = (const uint4*)(wpk + 460800);   // 16 KB zeros
    unsigned short* dpk = buf_b;          // packed texture; dead after trilin

    dim3 blk(256);

    prep_kern<<<1832, blk, 0, stream>>>(enc_w1, enc_w2, off_w, wc_w1, wc_w2, wc_w3, wpk);
    convert_data<<<1024, blk, 0, stream>>>(data, concat);
    pack_dpk<<<5120, blk, 0, stream>>>(data, dpk);

    // conv1: concat ch0-31 (zero-wt >=15) -> f1 (buf_a, NHWC 64)
    conv_mfma<<<dim3(256, 4, 1), blk, 0, stream>>>(
        concat, 232, 0, wp1, enc_b1, 1, 64, 64, buf_a, 64, 0, 0, 1, zp);
    // conv2: f1 -> feature (concat ch16-143)
    conv_mfma<<<dim3(256, 4, 2), blk, 0, stream>>>(
        buf_a, 64, 0, wp2, enc_b2, 2, 128, 128, concat, 232, 16, 0, 1, zp);
    // conv3: feature -> offsets (concat ch144-224)
    conv_mfma<<<dim3(256, 4, 2), blk, 0, stream>>>(
        concat, 232, 16, wp3, off_b, 4, 81, 128, concat, 232, 144, 0, 0, zp);
    // trilinear: offsets -> samples (in place in concat) + fp32 NCHW smp
    trilin_kern<<<1024, blk, 0, stream>>>(dpk, concat, smp);
    // conv5: concat 232(->256 pad) -> h1 (buf_a)
    conv_mfma<<<dim3(256, 4, 1), blk, 0, stream>>>(
        concat, 232, 0, wp5, wc_b1, 8, 64, 64, buf_a, 64, 0, 0, 1, zp);
    // conv6: h1 -> h2 (buf_b; overwrites dpk, which is dead now)
    conv_mfma<<<dim3(256, 4, 1), blk, 0, stream>>>(
        buf_a, 64, 0, wp6, wc_b2, 2, 64, 64, buf_b, 64, 0, 0, 1, zp);
    // conv7 + combine fused
    conv7_combine<<<dim3(256, 4), blk, 0, stream>>>(
        buf_b, wp7, wc_b3, concat, res_i, outp, zp);
}